// Round 6
// baseline (13635.350 us; speedup 1.0000x reference)
//
#include <hip/hip_runtime.h>
#include <cstdint>

#define NF 128   // node feature / hidden width
#define G4 512   // 4*H gates

typedef float v2f __attribute__((ext_vector_type(2)));

__device__ __forceinline__ float frcp(float x) { return __builtin_amdgcn_rcpf(x); }
__device__ __forceinline__ float ftanh(float x) {
  float e = __expf(2.f * x);
  return 1.f - 2.f * frcp(e + 1.f);
}

// DPP quad-perm lane exchanges (VALU, no LDS pipe, no barrier)
__device__ __forceinline__ float dpp_xor1(float x) {  // lane ^ 1 within quad
  int r = __builtin_amdgcn_update_dpp(0, __float_as_int(x), 0xB1, 0xF, 0xF, true);
  return __int_as_float(r);
}
__device__ __forceinline__ float dpp_xor2(float x) {  // lane ^ 2 within quad
  int r = __builtin_amdgcn_update_dpp(0, __float_as_int(x), 0x4E, 0xF, 0xF, true);
  return __int_as_float(r);
}

// ---------------- small utility kernels ----------------

__global__ void k_fill(float* p, float v, int n) {
  int i = blockIdx.x * blockDim.x + threadIdx.x;
  if (i < n) p[i] = v;
}

__global__ void k_detect_i64(const int* e, int npairs, int* flag) {
  int f = 1;
  for (int i = 1; i < 2 * npairs; i += 2)
    if (e[i] != 0) { f = 0; break; }
  *flag = f;
}

__device__ __forceinline__ int eidx(const void* edges, int i64, size_t pos) {
  if (i64) return (int)((const long long*)edges)[pos];
  return ((const int*)edges)[pos];
}

__global__ void k_count(const void* __restrict__ edges, const int* __restrict__ flag,
                        float* __restrict__ deg, int E) {
  int e = blockIdx.x * blockDim.x + threadIdx.x;
  if (e < E) {
    int d = eidx(edges, *flag, (size_t)E + e);
    unsafeAtomicAdd(&deg[d], 1.0f);
  }
}

__global__ void k_rsqrt(float* p, int n) {
  int i = blockIdx.x * blockDim.x + threadIdx.x;
  if (i < n) p[i] = rsqrtf(p[i]);
}

__global__ void k_t128(const float* __restrict__ in, float* __restrict__ out) {
  int n = blockIdx.x, k = threadIdx.x;
  out[n * 128 + k] = in[k * 128 + n];
}

__global__ void k_add(const float* a, const float* b, float* o, int n) {
  int i = blockIdx.x * blockDim.x + threadIdx.x;
  if (i < n) o[i] = a[i] + b[i];
}

// Quad-transpose W_hh for the LSTM: lane t=4u+p owns, for each gate g,
// columns [32p, 32p+32) of row g*128+u.  wp[t][g*32+k] = W[g*128+u][32p+k].
__global__ void k_wprep(const float* __restrict__ W, float* __restrict__ wp) {
  int t = blockIdx.x;        // 0..511
  int j = threadIdx.x;       // 0..127
  int u = t >> 2, p = t & 3;
  int g = j >> 5, k = j & 31;
  wp[(size_t)t * 128 + j] = W[(size_t)(g * 128 + u) * 128 + 32 * p + k];
}

// ---------------- GEMM: C[M,N] = A[M,K] @ B[N,K]^T (+bias) ----------------
__global__ __launch_bounds__(256)
void gemm_bt(const float* __restrict__ A, const float* __restrict__ B,
             const float* __restrict__ bias, float* __restrict__ C,
             int M, int N, int K) {
  __shared__ float As[32][68];
  __shared__ float Bs[32][68];
  const int bm = blockIdx.x * 64;
  const int bn = blockIdx.y * 64;
  const int tid = threadIdx.x;
  const int tm = (tid & 15) << 2;
  const int tn = (tid >> 4) << 2;
  float acc[4][4] = {};

  for (int k0 = 0; k0 < K; k0 += 32) {
#pragma unroll
    for (int l = 0; l < 2; ++l) {
      int idx = tid + l * 256;
      int row = idx >> 3;
      int k4 = (idx & 7) << 2;
      int ar = bm + row; ar = ar < M ? ar : M - 1;
      float4 av = *(const float4*)(A + (size_t)ar * K + k0 + k4);
      As[k4 + 0][row] = av.x; As[k4 + 1][row] = av.y;
      As[k4 + 2][row] = av.z; As[k4 + 3][row] = av.w;
      int br = bn + row; br = br < N ? br : N - 1;
      float4 bv = *(const float4*)(B + (size_t)br * K + k0 + k4);
      Bs[k4 + 0][row] = bv.x; Bs[k4 + 1][row] = bv.y;
      Bs[k4 + 2][row] = bv.z; Bs[k4 + 3][row] = bv.w;
    }
    __syncthreads();
#pragma unroll
    for (int kk = 0; kk < 32; ++kk) {
      float4 a = *(const float4*)&As[kk][tm];
      float4 b = *(const float4*)&Bs[kk][tn];
      float av[4] = {a.x, a.y, a.z, a.w};
      float bv[4] = {b.x, b.y, b.z, b.w};
#pragma unroll
      for (int i = 0; i < 4; ++i)
#pragma unroll
        for (int jj = 0; jj < 4; ++jj)
          acc[i][jj] = __builtin_fmaf(av[i], bv[jj], acc[i][jj]);
    }
    __syncthreads();
  }

  float4 bv4;
  if (bias) bv4 = *(const float4*)(bias + bn + tn);
  else bv4 = make_float4(0.f, 0.f, 0.f, 0.f);
#pragma unroll
  for (int i = 0; i < 4; ++i) {
    int row = bm + tm + i;
    if (row < M) {
      float4 v;
      v.x = acc[i][0] + bv4.x;
      v.y = acc[i][1] + bv4.y;
      v.z = acc[i][2] + bv4.z;
      v.w = acc[i][3] + bv4.w;
      *(float4*)(C + (size_t)row * N + bn + tn) = v;
    }
  }
}

// ---------------- GCN edge aggregation (atomic scatter) ----------------
__global__ __launch_bounds__(256)
void k_aggregate(const float* __restrict__ xw, const void* __restrict__ edges,
                 const int* __restrict__ flag, const float* __restrict__ dinv,
                 float* __restrict__ out, int E) {
  int e = blockIdx.x * 8 + (threadIdx.x >> 5);
  if (e >= E) return;
  int i64 = *flag;
  int s = eidx(edges, i64, e);
  int d = eidx(edges, i64, (size_t)E + e);
  float nrm = dinv[s] * dinv[d];
  int f4 = threadIdx.x & 31;
  float4 v = ((const float4*)xw)[(size_t)s * 32 + f4];
  float* op = out + (size_t)d * 128 + f4 * 4;
  unsafeAtomicAdd(op + 0, v.x * nrm);
  unsafeAtomicAdd(op + 1, v.y * nrm);
  unsafeAtomicAdd(op + 2, v.z * nrm);
  unsafeAtomicAdd(op + 3, v.w * nrm);
}

__global__ void k_finish(float* __restrict__ h, const float* __restrict__ xw,
                         const float* __restrict__ dinv, const float* __restrict__ b,
                         int N) {
  int i4 = blockIdx.x * blockDim.x + threadIdx.x;
  if (i4 >= N * 32) return;
  int n = i4 >> 5;
  int f4 = (i4 & 31) << 2;
  float di = dinv[n];
  float s = di * di;
  float4 ag = ((const float4*)h)[i4];
  float4 xv = ((const float4*)xw)[i4];
  float4 bv = *(const float4*)(b + f4);
  float4 r;
  r.x = fmaxf(__builtin_fmaf(xv.x, s, ag.x) + bv.x, 0.f);
  r.y = fmaxf(__builtin_fmaf(xv.y, s, ag.y) + bv.y, 0.f);
  r.z = fmaxf(__builtin_fmaf(xv.z, s, ag.z) + bv.z, 0.f);
  r.w = fmaxf(__builtin_fmaf(xv.w, s, ag.w) + bv.w, 0.f);
  ((float4*)h)[i4] = r;
}

// ---------------- sequential LSTM scan ----------------
// 512 threads, quad 4u..4u+3 owns unit u (see R4 comments for data layout).
// LDS cap (>80KB) keeps occupancy at 1 WG = 2 waves/EU -> 256-VGPR budget.
// R5 showed budget alone is NOT enough: the allocator REMATERIALIZES the
// invariant weight loads inside the loop (VGPR stayed 88). Fix: pipe each
// weight value through an empty asm "+v" BEFORE the loop -- the asm becomes
// the producer, so the values cannot be rematerialized from memory and must
// stay resident in VGPRs across the 20000-step loop.
__global__ __launch_bounds__(512)
__attribute__((amdgpu_waves_per_eu(2, 2)))
void k_lstm(const float* __restrict__ g_in, const float* __restrict__ wp,
            float* __restrict__ hs, int T) {
  const int t = threadIdx.x;
  const int q = t >> 2;        // unit 0..127
  const int pos = t & 3;       // gate slot: 0=i 1=f 2=g 3=o
  const int row = pos * 128 + q;

  __shared__ __align__(16) float hbuf[2][144];   // skew: h[q] at q + 4*(q>>5)
  __shared__ float lds_cap[20736];               // 82944 B occupancy anchor

  if (t == 0) {
    volatile float* vp = lds_cap;
    vp[0] = 0.f;
  }

  // 128 weight floats in VGPRs as 64 packed pairs
  v2f wq[64];
  {
    const float4* wr = (const float4*)(wp + (size_t)t * 128);
#pragma unroll
    for (int k = 0; k < 32; ++k) {
      float4 wv = wr[k];
      wq[2 * k + 0] = (v2f){wv.x, wv.y};
      wq[2 * k + 1] = (v2f){wv.z, wv.w};
    }
  }
  // REGISTER PIN: make wq unrematerializable (asm is now the producer).
#pragma unroll
  for (int k = 0; k < 64; k += 8) {
    asm volatile("" : "+v"(wq[k + 0]), "+v"(wq[k + 1]), "+v"(wq[k + 2]),
                      "+v"(wq[k + 3]), "+v"(wq[k + 4]), "+v"(wq[k + 5]),
                      "+v"(wq[k + 6]), "+v"(wq[k + 7]));
  }

  if (t < 144) { hbuf[0][t] = 0.f; hbuf[1][t] = 0.f; }
  float c = 0.f;
  float gn = g_in[row];
  __syncthreads();

  int pb = 0;
  const bool isg = (pos == 2);
  const bool sw1 = (pos & 1);
  const bool sw2 = (pos & 2) != 0;

  for (int step = 0; step < T; ++step) {
    float gcur = gn;
    size_t nb = (size_t)(step + 1 < T ? step + 1 : step) * G4;
    gn = g_in[nb + row];               // prefetch next step's input

    const float4* hb = (const float4*)&hbuf[pb][36 * pos];
    v2f a0 = {0.f, 0.f}, a1 = {0.f, 0.f}, a2 = {0.f, 0.f}, a3 = {0.f, 0.f};
#pragma unroll
    for (int jj = 0; jj < 8; ++jj) {
      float4 hv = hb[jj];
      v2f hlo = (v2f){hv.x, hv.y};
      v2f hhi = (v2f){hv.z, hv.w};
      a0 = __builtin_elementwise_fma(wq[0 * 16 + 2 * jj], hlo, a0);
      a0 = __builtin_elementwise_fma(wq[0 * 16 + 2 * jj + 1], hhi, a0);
      a1 = __builtin_elementwise_fma(wq[1 * 16 + 2 * jj], hlo, a1);
      a1 = __builtin_elementwise_fma(wq[1 * 16 + 2 * jj + 1], hhi, a1);
      a2 = __builtin_elementwise_fma(wq[2 * 16 + 2 * jj], hlo, a2);
      a2 = __builtin_elementwise_fma(wq[2 * 16 + 2 * jj + 1], hhi, a2);
      a3 = __builtin_elementwise_fma(wq[3 * 16 + 2 * jj], hlo, a3);
      a3 = __builtin_elementwise_fma(wq[3 * 16 + 2 * jj + 1], hhi, a3);
    }
    float s0 = a0.x + a0.y;
    float s1 = a1.x + a1.y;
    float s2 = a2.x + a2.y;
    float s3 = a3.x + a3.y;

    // quad butterfly-REDUCE: lane p ends with gate p's full preactivation
    float send_lo = sw1 ? s0 : s1;
    float send_hi = sw1 ? s2 : s3;
    float keep_lo = sw1 ? s1 : s0;
    float keep_hi = sw1 ? s3 : s2;
    float r_lo = keep_lo + dpp_xor1(send_lo);   // gate (p&1)
    float r_hi = keep_hi + dpp_xor1(send_hi);   // gate (p&1)+2
    float send2 = sw2 ? r_lo : r_hi;
    float keep2 = sw2 ? r_hi : r_lo;
    float x = keep2 + dpp_xor2(send2) + gcur;   // gate p total

    // activation: pos==2 -> tanh (as 2*sig(2x)-1), else sigmoid
    float xs = isg ? 2.f * x : x;
    float e = __expf(-xs);
    float r = frcp(1.f + e);
    float a = isg ? 2.f * r - 1.f : r;

    // quad butterfly-GATHER: every lane collects all 4 gate activations
    float b = dpp_xor1(a);
    float c2 = dpp_xor2(a);
    float d2 = dpp_xor2(b);
    float p0 = sw1 ? b : a;
    float p1 = sw1 ? a : b;
    float p2 = sw1 ? d2 : c2;
    float p3 = sw1 ? c2 : d2;
    float i_ = sw2 ? p2 : p0;
    float f_ = sw2 ? p3 : p1;
    float g_ = sw2 ? p0 : p2;
    float o_ = sw2 ? p1 : p3;

    c = __builtin_fmaf(f_, c, i_ * g_);   // all 4 lanes redundantly
    float h = o_ * ftanh(c);

    pb ^= 1;
    if (pos == 0) {
      hbuf[pb][q + ((q >> 5) << 2)] = h;
      hs[(size_t)step * NF + q] = h;
    }
    __syncthreads();
  }
}

// ---------------- host launch ----------------

extern "C" void kernel_launch(void* const* d_in, const int* in_sizes, int n_in,
                              void* d_out, int out_size, void* d_ws, size_t ws_size,
                              hipStream_t stream) {
  const float* x     = (const float*)d_in[0];
  const void* edges  = d_in[1];
  const float* W1    = (const float*)d_in[2];
  const float* b1    = (const float*)d_in[3];
  const float* W2    = (const float*)d_in[4];
  const float* b2    = (const float*)d_in[5];
  const float* W_ih  = (const float*)d_in[6];
  const float* W_hh  = (const float*)d_in[7];
  const float* b_ih  = (const float*)d_in[8];
  const float* b_hh  = (const float*)d_in[9];
  const float* W_lin = (const float*)d_in[10];
  const float* b_lin = (const float*)d_in[11];
  float* out = (float*)d_out;

  const int N = in_sizes[0] / NF;  // 20000
  const int E = in_sizes[1] / 2;   // 640000
  const int OUTF = 64;

  char* base = (char*)d_ws;
  size_t off = 0;
  auto alloc = [&](size_t b) {
    char* p = base + off;
    off += (b + 255) & ~(size_t)255;
    return p;
  };
  float* dinv = (float*)alloc((size_t)N * 4);
  float* W1T  = (float*)alloc(128 * 128 * 4);
  float* W2T  = (float*)alloc(128 * 128 * 4);
  float* wp   = (float*)alloc(512 * 128 * 4);
  float* bsum = (float*)alloc(512 * 4);
  int*   flag = (int*)alloc(256);
  float* bufA = (float*)alloc((size_t)N * NF * 4);
  float* bufB = (float*)alloc((size_t)N * NF * 4);
  float* bufC = (float*)alloc((size_t)N * NF * 4);
  float* g_in = (float*)alloc((size_t)N * (size_t)G4 * 4);
  if (off > ws_size) return;

  k_fill<<<(N + 255) / 256, 256, 0, stream>>>(dinv, 1.0f, N);
  k_detect_i64<<<1, 1, 0, stream>>>((const int*)edges, 1024, flag);
  k_count<<<(E + 255) / 256, 256, 0, stream>>>(edges, flag, dinv, E);
  k_rsqrt<<<(N + 255) / 256, 256, 0, stream>>>(dinv, N);
  k_t128<<<128, 128, 0, stream>>>(W1, W1T);
  k_t128<<<128, 128, 0, stream>>>(W2, W2T);
  k_wprep<<<512, 128, 0, stream>>>(W_hh, wp);
  k_add<<<2, 256, 0, stream>>>(b_ih, b_hh, bsum, 512);

  const int mg = (N + 63) / 64;

  gemm_bt<<<dim3(mg, 2), 256, 0, stream>>>(x, W1T, nullptr, bufA, N, NF, NF);
  hipMemsetAsync(bufB, 0, (size_t)N * NF * 4, stream);
  k_aggregate<<<(E + 7) / 8, 256, 0, stream>>>(bufA, edges, flag, dinv, bufB, E);
  k_finish<<<(N * 32 + 255) / 256, 256, 0, stream>>>(bufB, bufA, dinv, b1, N);

  gemm_bt<<<dim3(mg, 2), 256, 0, stream>>>(bufB, W2T, nullptr, bufA, N, NF, NF);
  hipMemsetAsync(bufC, 0, (size_t)N * NF * 4, stream);
  k_aggregate<<<(E + 7) / 8, 256, 0, stream>>>(bufA, edges, flag, dinv, bufC, E);
  k_finish<<<(N * 32 + 255) / 256, 256, 0, stream>>>(bufC, bufA, dinv, b2, N);

  gemm_bt<<<dim3(mg, 8), 256, 0, stream>>>(bufC, W_ih, bsum, g_in, N, G4, NF);

  k_lstm<<<1, 512, 0, stream>>>(g_in, wp, bufB, N);

  gemm_bt<<<dim3(mg, 1), 256, 0, stream>>>(bufB, W_lin, b_lin, out, N, OUTF, NF);
}

// Round 7
// 13086.667 us; speedup vs baseline: 1.0419x; 1.0419x over previous
//
#include <hip/hip_runtime.h>
#include <cstdint>

#define NF 128   // node feature / hidden width
#define G4 512   // 4*H gates

typedef float v2f __attribute__((ext_vector_type(2)));

__device__ __forceinline__ float frcp(float x) { return __builtin_amdgcn_rcpf(x); }
__device__ __forceinline__ float ftanh(float x) {
  float e = __expf(2.f * x);
  return 1.f - 2.f * frcp(e + 1.f);
}

// DPP quad-perm lane exchanges (VALU, no LDS pipe, no barrier)
__device__ __forceinline__ float dpp_xor1(float x) {  // lane ^ 1 within quad
  int r = __builtin_amdgcn_update_dpp(0, __float_as_int(x), 0xB1, 0xF, 0xF, true);
  return __int_as_float(r);
}
__device__ __forceinline__ float dpp_xor2(float x) {  // lane ^ 2 within quad
  int r = __builtin_amdgcn_update_dpp(0, __float_as_int(x), 0x4E, 0xF, 0xF, true);
  return __int_as_float(r);
}

// ---------------- small utility kernels ----------------

__global__ void k_fill(float* p, float v, int n) {
  int i = blockIdx.x * blockDim.x + threadIdx.x;
  if (i < n) p[i] = v;
}

__global__ void k_detect_i64(const int* e, int npairs, int* flag) {
  int f = 1;
  for (int i = 1; i < 2 * npairs; i += 2)
    if (e[i] != 0) { f = 0; break; }
  *flag = f;
}

__device__ __forceinline__ int eidx(const void* edges, int i64, size_t pos) {
  if (i64) return (int)((const long long*)edges)[pos];
  return ((const int*)edges)[pos];
}

__global__ void k_count(const void* __restrict__ edges, const int* __restrict__ flag,
                        float* __restrict__ deg, int E) {
  int e = blockIdx.x * blockDim.x + threadIdx.x;
  if (e < E) {
    int d = eidx(edges, *flag, (size_t)E + e);
    unsafeAtomicAdd(&deg[d], 1.0f);
  }
}

__global__ void k_rsqrt(float* p, int n) {
  int i = blockIdx.x * blockDim.x + threadIdx.x;
  if (i < n) p[i] = rsqrtf(p[i]);
}

__global__ void k_t128(const float* __restrict__ in, float* __restrict__ out) {
  int n = blockIdx.x, k = threadIdx.x;
  out[n * 128 + k] = in[k * 128 + n];
}

__global__ void k_add(const float* a, const float* b, float* o, int n) {
  int i = blockIdx.x * blockDim.x + threadIdx.x;
  if (i < n) o[i] = a[i] + b[i];
}

// Quad-transpose W_hh for the LSTM: lane t=4u+p owns, for each gate g,
// columns [32p, 32p+32) of row g*128+u.  wp[t][g*32+k] = W[g*128+u][32p+k].
__global__ void k_wprep(const float* __restrict__ W, float* __restrict__ wp) {
  int t = blockIdx.x;        // 0..511
  int j = threadIdx.x;       // 0..127
  int u = t >> 2, p = t & 3;
  int g = j >> 5, k = j & 31;
  wp[(size_t)t * 128 + j] = W[(size_t)(g * 128 + u) * 128 + 32 * p + k];
}

// ---------------- GEMM: C[M,N] = A[M,K] @ B[N,K]^T (+bias) ----------------
__global__ __launch_bounds__(256)
void gemm_bt(const float* __restrict__ A, const float* __restrict__ B,
             const float* __restrict__ bias, float* __restrict__ C,
             int M, int N, int K) {
  __shared__ float As[32][68];
  __shared__ float Bs[32][68];
  const int bm = blockIdx.x * 64;
  const int bn = blockIdx.y * 64;
  const int tid = threadIdx.x;
  const int tm = (tid & 15) << 2;
  const int tn = (tid >> 4) << 2;
  float acc[4][4] = {};

  for (int k0 = 0; k0 < K; k0 += 32) {
#pragma unroll
    for (int l = 0; l < 2; ++l) {
      int idx = tid + l * 256;
      int row = idx >> 3;
      int k4 = (idx & 7) << 2;
      int ar = bm + row; ar = ar < M ? ar : M - 1;
      float4 av = *(const float4*)(A + (size_t)ar * K + k0 + k4);
      As[k4 + 0][row] = av.x; As[k4 + 1][row] = av.y;
      As[k4 + 2][row] = av.z; As[k4 + 3][row] = av.w;
      int br = bn + row; br = br < N ? br : N - 1;
      float4 bv = *(const float4*)(B + (size_t)br * K + k0 + k4);
      Bs[k4 + 0][row] = bv.x; Bs[k4 + 1][row] = bv.y;
      Bs[k4 + 2][row] = bv.z; Bs[k4 + 3][row] = bv.w;
    }
    __syncthreads();
#pragma unroll
    for (int kk = 0; kk < 32; ++kk) {
      float4 a = *(const float4*)&As[kk][tm];
      float4 b = *(const float4*)&Bs[kk][tn];
      float av[4] = {a.x, a.y, a.z, a.w};
      float bv[4] = {b.x, b.y, b.z, b.w};
#pragma unroll
      for (int i = 0; i < 4; ++i)
#pragma unroll
        for (int jj = 0; jj < 4; ++jj)
          acc[i][jj] = __builtin_fmaf(av[i], bv[jj], acc[i][jj]);
    }
    __syncthreads();
  }

  float4 bv4;
  if (bias) bv4 = *(const float4*)(bias + bn + tn);
  else bv4 = make_float4(0.f, 0.f, 0.f, 0.f);
#pragma unroll
  for (int i = 0; i < 4; ++i) {
    int row = bm + tm + i;
    if (row < M) {
      float4 v;
      v.x = acc[i][0] + bv4.x;
      v.y = acc[i][1] + bv4.y;
      v.z = acc[i][2] + bv4.z;
      v.w = acc[i][3] + bv4.w;
      *(float4*)(C + (size_t)row * N + bn + tn) = v;
    }
  }
}

// ---------------- GCN edge aggregation (atomic scatter) ----------------
__global__ __launch_bounds__(256)
void k_aggregate(const float* __restrict__ xw, const void* __restrict__ edges,
                 const int* __restrict__ flag, const float* __restrict__ dinv,
                 float* __restrict__ out, int E) {
  int e = blockIdx.x * 8 + (threadIdx.x >> 5);
  if (e >= E) return;
  int i64 = *flag;
  int s = eidx(edges, i64, e);
  int d = eidx(edges, i64, (size_t)E + e);
  float nrm = dinv[s] * dinv[d];
  int f4 = threadIdx.x & 31;
  float4 v = ((const float4*)xw)[(size_t)s * 32 + f4];
  float* op = out + (size_t)d * 128 + f4 * 4;
  unsafeAtomicAdd(op + 0, v.x * nrm);
  unsafeAtomicAdd(op + 1, v.y * nrm);
  unsafeAtomicAdd(op + 2, v.z * nrm);
  unsafeAtomicAdd(op + 3, v.w * nrm);
}

__global__ void k_finish(float* __restrict__ h, const float* __restrict__ xw,
                         const float* __restrict__ dinv, const float* __restrict__ b,
                         int N) {
  int i4 = blockIdx.x * blockDim.x + threadIdx.x;
  if (i4 >= N * 32) return;
  int n = i4 >> 5;
  int f4 = (i4 & 31) << 2;
  float di = dinv[n];
  float s = di * di;
  float4 ag = ((const float4*)h)[i4];
  float4 xv = ((const float4*)xw)[i4];
  float4 bv = *(const float4*)(b + f4);
  float4 r;
  r.x = fmaxf(__builtin_fmaf(xv.x, s, ag.x) + bv.x, 0.f);
  r.y = fmaxf(__builtin_fmaf(xv.y, s, ag.y) + bv.y, 0.f);
  r.z = fmaxf(__builtin_fmaf(xv.z, s, ag.z) + bv.z, 0.f);
  r.w = fmaxf(__builtin_fmaf(xv.w, s, ag.w) + bv.w, 0.f);
  ((float4*)h)[i4] = r;
}

// ---------------- sequential LSTM scan ----------------
// 512 threads, quad 4u..4u+3 owns unit u (layout: see k_wprep).
// WEIGHTS LIVE IN PHYSICAL v128..v255, loaded ONCE by an asm preload whose
// clobber list reserves them (VGPR_Count forced to 256 -> 2 waves/EU, which
// the 84KB LDS cap makes free). The in-loop FMA block references them by
// NAME, so no allocator heuristic (remat/spill: R2-R6, VGPR stuck at 80-88,
// ~256KB/step reloads at L1 BW = the measured 1374 cyc/step) can evict them.
__global__ __launch_bounds__(512)
__attribute__((amdgpu_waves_per_eu(2, 2)))
void k_lstm(const float* __restrict__ g_in, const float* __restrict__ wp,
            float* __restrict__ hs, int T) {
  const int t = threadIdx.x;
  const int q = t >> 2;        // unit 0..127
  const int pos = t & 3;       // gate slot: 0=i 1=f 2=g 3=o
  const int row = pos * 128 + q;

  __shared__ __align__(16) float hbuf[2][144];   // skew: h[q] at q + 4*(q>>5)
  __shared__ float lds_cap[20736];               // 82944 B occupancy anchor

  if (t == 0) {
    volatile float* vp = lds_cap;
    vp[0] = 0.f;
  }

  // -------- one-time weight preload into physical v128..v255 --------
  {
    const float* wr = wp + (size_t)t * 128;
    asm volatile(
      "global_load_dwordx4 v[128:131], %0, off\n\t"
      "global_load_dwordx4 v[132:135], %0, off offset:16\n\t"
      "global_load_dwordx4 v[136:139], %0, off offset:32\n\t"
      "global_load_dwordx4 v[140:143], %0, off offset:48\n\t"
      "global_load_dwordx4 v[144:147], %0, off offset:64\n\t"
      "global_load_dwordx4 v[148:151], %0, off offset:80\n\t"
      "global_load_dwordx4 v[152:155], %0, off offset:96\n\t"
      "global_load_dwordx4 v[156:159], %0, off offset:112\n\t"
      "global_load_dwordx4 v[160:163], %0, off offset:128\n\t"
      "global_load_dwordx4 v[164:167], %0, off offset:144\n\t"
      "global_load_dwordx4 v[168:171], %0, off offset:160\n\t"
      "global_load_dwordx4 v[172:175], %0, off offset:176\n\t"
      "global_load_dwordx4 v[176:179], %0, off offset:192\n\t"
      "global_load_dwordx4 v[180:183], %0, off offset:208\n\t"
      "global_load_dwordx4 v[184:187], %0, off offset:224\n\t"
      "global_load_dwordx4 v[188:191], %0, off offset:240\n\t"
      "global_load_dwordx4 v[192:195], %0, off offset:256\n\t"
      "global_load_dwordx4 v[196:199], %0, off offset:272\n\t"
      "global_load_dwordx4 v[200:203], %0, off offset:288\n\t"
      "global_load_dwordx4 v[204:207], %0, off offset:304\n\t"
      "global_load_dwordx4 v[208:211], %0, off offset:320\n\t"
      "global_load_dwordx4 v[212:215], %0, off offset:336\n\t"
      "global_load_dwordx4 v[216:219], %0, off offset:352\n\t"
      "global_load_dwordx4 v[220:223], %0, off offset:368\n\t"
      "global_load_dwordx4 v[224:227], %0, off offset:384\n\t"
      "global_load_dwordx4 v[228:231], %0, off offset:400\n\t"
      "global_load_dwordx4 v[232:235], %0, off offset:416\n\t"
      "global_load_dwordx4 v[236:239], %0, off offset:432\n\t"
      "global_load_dwordx4 v[240:243], %0, off offset:448\n\t"
      "global_load_dwordx4 v[244:247], %0, off offset:464\n\t"
      "global_load_dwordx4 v[248:251], %0, off offset:480\n\t"
      "global_load_dwordx4 v[252:255], %0, off offset:496\n\t"
      "s_waitcnt vmcnt(0)"
      :: "v"(wr)
      : "v128","v129","v130","v131","v132","v133","v134","v135",
        "v136","v137","v138","v139","v140","v141","v142","v143",
        "v144","v145","v146","v147","v148","v149","v150","v151",
        "v152","v153","v154","v155","v156","v157","v158","v159",
        "v160","v161","v162","v163","v164","v165","v166","v167",
        "v168","v169","v170","v171","v172","v173","v174","v175",
        "v176","v177","v178","v179","v180","v181","v182","v183",
        "v184","v185","v186","v187","v188","v189","v190","v191",
        "v192","v193","v194","v195","v196","v197","v198","v199",
        "v200","v201","v202","v203","v204","v205","v206","v207",
        "v208","v209","v210","v211","v212","v213","v214","v215",
        "v216","v217","v218","v219","v220","v221","v222","v223",
        "v224","v225","v226","v227","v228","v229","v230","v231",
        "v232","v233","v234","v235","v236","v237","v238","v239",
        "v240","v241","v242","v243","v244","v245","v246","v247",
        "v248","v249","v250","v251","v252","v253","v254","v255");
  }

  if (t < 144) { hbuf[0][t] = 0.f; hbuf[1][t] = 0.f; }
  float c = 0.f;
  float gn = g_in[row];
  __syncthreads();

  int pb = 0;
  const bool isg = (pos == 2);
  const bool sw1 = (pos & 1);
  const bool sw2 = (pos & 2) != 0;

  for (int step = 0; step < T; ++step) {
    float gcur = gn;
    size_t nb = (size_t)(step + 1 < T ? step + 1 : step) * G4;
    gn = g_in[nb + row];               // prefetch next step's input

    const float4* hb = (const float4*)&hbuf[pb][36 * pos];
    float4 hv0 = hb[0], hv1 = hb[1], hv2 = hb[2], hv3 = hb[3];
    float4 hv4 = hb[4], hv5 = hb[5], hv6 = hb[6], hv7 = hb[7];
    v2f h0 = {hv0.x, hv0.y}, h1 = {hv0.z, hv0.w};
    v2f h2 = {hv1.x, hv1.y}, h3 = {hv1.z, hv1.w};
    v2f h4 = {hv2.x, hv2.y}, h5 = {hv2.z, hv2.w};
    v2f h6 = {hv3.x, hv3.y}, h7 = {hv3.z, hv3.w};
    v2f h8 = {hv4.x, hv4.y}, h9 = {hv4.z, hv4.w};
    v2f h10 = {hv5.x, hv5.y}, h11 = {hv5.z, hv5.w};
    v2f h12 = {hv6.x, hv6.y}, h13 = {hv6.z, hv6.w};
    v2f h14 = {hv7.x, hv7.y}, h15 = {hv7.z, hv7.w};

    v2f a0 = {0.f, 0.f}, a1 = {0.f, 0.f}, a2 = {0.f, 0.f}, a3 = {0.f, 0.f};
    // 64 pk-FMAs on hard-coded weight regs, round-robin over the 4
    // independent gate accumulators so consecutive instrs never depend.
    asm volatile(
      "v_pk_fma_f32 %0, v[128:129], %4, %0\n\t"
      "v_pk_fma_f32 %1, v[160:161], %4, %1\n\t"
      "v_pk_fma_f32 %2, v[192:193], %4, %2\n\t"
      "v_pk_fma_f32 %3, v[224:225], %4, %3\n\t"
      "v_pk_fma_f32 %0, v[130:131], %5, %0\n\t"
      "v_pk_fma_f32 %1, v[162:163], %5, %1\n\t"
      "v_pk_fma_f32 %2, v[194:195], %5, %2\n\t"
      "v_pk_fma_f32 %3, v[226:227], %5, %3\n\t"
      "v_pk_fma_f32 %0, v[132:133], %6, %0\n\t"
      "v_pk_fma_f32 %1, v[164:165], %6, %1\n\t"
      "v_pk_fma_f32 %2, v[196:197], %6, %2\n\t"
      "v_pk_fma_f32 %3, v[228:229], %6, %3\n\t"
      "v_pk_fma_f32 %0, v[134:135], %7, %0\n\t"
      "v_pk_fma_f32 %1, v[166:167], %7, %1\n\t"
      "v_pk_fma_f32 %2, v[198:199], %7, %2\n\t"
      "v_pk_fma_f32 %3, v[230:231], %7, %3\n\t"
      "v_pk_fma_f32 %0, v[136:137], %8, %0\n\t"
      "v_pk_fma_f32 %1, v[168:169], %8, %1\n\t"
      "v_pk_fma_f32 %2, v[200:201], %8, %2\n\t"
      "v_pk_fma_f32 %3, v[232:233], %8, %3\n\t"
      "v_pk_fma_f32 %0, v[138:139], %9, %0\n\t"
      "v_pk_fma_f32 %1, v[170:171], %9, %1\n\t"
      "v_pk_fma_f32 %2, v[202:203], %9, %2\n\t"
      "v_pk_fma_f32 %3, v[234:235], %9, %3\n\t"
      "v_pk_fma_f32 %0, v[140:141], %10, %0\n\t"
      "v_pk_fma_f32 %1, v[172:173], %10, %1\n\t"
      "v_pk_fma_f32 %2, v[204:205], %10, %2\n\t"
      "v_pk_fma_f32 %3, v[236:237], %10, %3\n\t"
      "v_pk_fma_f32 %0, v[142:143], %11, %0\n\t"
      "v_pk_fma_f32 %1, v[174:175], %11, %1\n\t"
      "v_pk_fma_f32 %2, v[206:207], %11, %2\n\t"
      "v_pk_fma_f32 %3, v[238:239], %11, %3\n\t"
      "v_pk_fma_f32 %0, v[144:145], %12, %0\n\t"
      "v_pk_fma_f32 %1, v[176:177], %12, %1\n\t"
      "v_pk_fma_f32 %2, v[208:209], %12, %2\n\t"
      "v_pk_fma_f32 %3, v[240:241], %12, %3\n\t"
      "v_pk_fma_f32 %0, v[146:147], %13, %0\n\t"
      "v_pk_fma_f32 %1, v[178:179], %13, %1\n\t"
      "v_pk_fma_f32 %2, v[210:211], %13, %2\n\t"
      "v_pk_fma_f32 %3, v[242:243], %13, %3\n\t"
      "v_pk_fma_f32 %0, v[148:149], %14, %0\n\t"
      "v_pk_fma_f32 %1, v[180:181], %14, %1\n\t"
      "v_pk_fma_f32 %2, v[212:213], %14, %2\n\t"
      "v_pk_fma_f32 %3, v[244:245], %14, %3\n\t"
      "v_pk_fma_f32 %0, v[150:151], %15, %0\n\t"
      "v_pk_fma_f32 %1, v[182:183], %15, %1\n\t"
      "v_pk_fma_f32 %2, v[214:215], %15, %2\n\t"
      "v_pk_fma_f32 %3, v[246:247], %15, %3\n\t"
      "v_pk_fma_f32 %0, v[152:153], %16, %0\n\t"
      "v_pk_fma_f32 %1, v[184:185], %16, %1\n\t"
      "v_pk_fma_f32 %2, v[216:217], %16, %2\n\t"
      "v_pk_fma_f32 %3, v[248:249], %16, %3\n\t"
      "v_pk_fma_f32 %0, v[154:155], %17, %0\n\t"
      "v_pk_fma_f32 %1, v[186:187], %17, %1\n\t"
      "v_pk_fma_f32 %2, v[218:219], %17, %2\n\t"
      "v_pk_fma_f32 %3, v[250:251], %17, %3\n\t"
      "v_pk_fma_f32 %0, v[156:157], %18, %0\n\t"
      "v_pk_fma_f32 %1, v[188:189], %18, %1\n\t"
      "v_pk_fma_f32 %2, v[220:221], %18, %2\n\t"
      "v_pk_fma_f32 %3, v[252:253], %18, %3\n\t"
      "v_pk_fma_f32 %0, v[158:159], %19, %0\n\t"
      "v_pk_fma_f32 %1, v[190:191], %19, %1\n\t"
      "v_pk_fma_f32 %2, v[222:223], %19, %2\n\t"
      "v_pk_fma_f32 %3, v[254:255], %19, %3"
      : "+v"(a0), "+v"(a1), "+v"(a2), "+v"(a3)
      : "v"(h0), "v"(h1), "v"(h2), "v"(h3), "v"(h4), "v"(h5), "v"(h6), "v"(h7),
        "v"(h8), "v"(h9), "v"(h10), "v"(h11), "v"(h12), "v"(h13), "v"(h14), "v"(h15));

    float s0 = a0.x + a0.y;
    float s1 = a1.x + a1.y;
    float s2 = a2.x + a2.y;
    float s3 = a3.x + a3.y;

    // quad butterfly-REDUCE: lane p ends with gate p's full preactivation
    float send_lo = sw1 ? s0 : s1;
    float send_hi = sw1 ? s2 : s3;
    float keep_lo = sw1 ? s1 : s0;
    float keep_hi = sw1 ? s3 : s2;
    float r_lo = keep_lo + dpp_xor1(send_lo);   // gate (p&1)
    float r_hi = keep_hi + dpp_xor1(send_hi);   // gate (p&1)+2
    float send2 = sw2 ? r_lo : r_hi;
    float keep2 = sw2 ? r_hi : r_lo;
    float x = keep2 + dpp_xor2(send2) + gcur;   // gate p total

    // activation: pos==2 -> tanh (as 2*sig(2x)-1), else sigmoid
    float xs = isg ? 2.f * x : x;
    float e = __expf(-xs);
    float r = frcp(1.f + e);
    float a = isg ? 2.f * r - 1.f : r;

    // quad butterfly-GATHER: every lane collects all 4 gate activations
    float b = dpp_xor1(a);
    float c2 = dpp_xor2(a);
    float d2 = dpp_xor2(b);
    float p0 = sw1 ? b : a;
    float p1 = sw1 ? a : b;
    float p2 = sw1 ? d2 : c2;
    float p3 = sw1 ? c2 : d2;
    float i_ = sw2 ? p2 : p0;
    float f_ = sw2 ? p3 : p1;
    float g_ = sw2 ? p0 : p2;
    float o_ = sw2 ? p1 : p3;

    c = __builtin_fmaf(f_, c, i_ * g_);   // all 4 lanes redundantly
    float h = o_ * ftanh(c);

    pb ^= 1;
    if (pos == 0) {
      hbuf[pb][q + ((q >> 5) << 2)] = h;
      hs[(size_t)step * NF + q] = h;
    }
    __syncthreads();
  }
}

// ---------------- host launch ----------------

extern "C" void kernel_launch(void* const* d_in, const int* in_sizes, int n_in,
                              void* d_out, int out_size, void* d_ws, size_t ws_size,
                              hipStream_t stream) {
  const float* x     = (const float*)d_in[0];
  const void* edges  = d_in[1];
  const float* W1    = (const float*)d_in[2];
  const float* b1    = (const float*)d_in[3];
  const float* W2    = (const float*)d_in[4];
  const float* b2    = (const float*)d_in[5];
  const float* W_ih  = (const float*)d_in[6];
  const float* W_hh  = (const float*)d_in[7];
  const float* b_ih  = (const float*)d_in[8];
  const float* b_hh  = (const float*)d_in[9];
  const float* W_lin = (const float*)d_in[10];
  const float* b_lin = (const float*)d_in[11];
  float* out = (float*)d_out;

  const int N = in_sizes[0] / NF;  // 20000
  const int E = in_sizes[1] / 2;   // 640000
  const int OUTF = 64;

  char* base = (char*)d_ws;
  size_t off = 0;
  auto alloc = [&](size_t b) {
    char* p = base + off;
    off += (b + 255) & ~(size_t)255;
    return p;
  };
  float* dinv = (float*)alloc((size_t)N * 4);
  float* W1T  = (float*)alloc(128 * 128 * 4);
  float* W2T  = (float*)alloc(128 * 128 * 4);
  float* wp   = (float*)alloc(512 * 128 * 4);
  float* bsum = (float*)alloc(512 * 4);
  int*   flag = (int*)alloc(256);
  float* bufA = (float*)alloc((size_t)N * NF * 4);
  float* bufB = (float*)alloc((size_t)N * NF * 4);
  float* bufC = (float*)alloc((size_t)N * NF * 4);
  float* g_in = (float*)alloc((size_t)N * (size_t)G4 * 4);
  if (off > ws_size) return;

  k_fill<<<(N + 255) / 256, 256, 0, stream>>>(dinv, 1.0f, N);
  k_detect_i64<<<1, 1, 0, stream>>>((const int*)edges, 1024, flag);
  k_count<<<(E + 255) / 256, 256, 0, stream>>>(edges, flag, dinv, E);
  k_rsqrt<<<(N + 255) / 256, 256, 0, stream>>>(dinv, N);
  k_t128<<<128, 128, 0, stream>>>(W1, W1T);
  k_t128<<<128, 128, 0, stream>>>(W2, W2T);
  k_wprep<<<512, 128, 0, stream>>>(W_hh, wp);
  k_add<<<2, 256, 0, stream>>>(b_ih, b_hh, bsum, 512);

  const int mg = (N + 63) / 64;

  gemm_bt<<<dim3(mg, 2), 256, 0, stream>>>(x, W1T, nullptr, bufA, N, NF, NF);
  hipMemsetAsync(bufB, 0, (size_t)N * NF * 4, stream);
  k_aggregate<<<(E + 7) / 8, 256, 0, stream>>>(bufA, edges, flag, dinv, bufB, E);
  k_finish<<<(N * 32 + 255) / 256, 256, 0, stream>>>(bufB, bufA, dinv, b1, N);

  gemm_bt<<<dim3(mg, 2), 256, 0, stream>>>(bufB, W2T, nullptr, bufA, N, NF, NF);
  hipMemsetAsync(bufC, 0, (size_t)N * NF * 4, stream);
  k_aggregate<<<(E + 7) / 8, 256, 0, stream>>>(bufA, edges, flag, dinv, bufC, E);
  k_finish<<<(N * 32 + 255) / 256, 256, 0, stream>>>(bufC, bufA, dinv, b2, N);

  gemm_bt<<<dim3(mg, 8), 256, 0, stream>>>(bufC, W_ih, bsum, g_in, N, G4, NF);

  k_lstm<<<1, 512, 0, stream>>>(g_in, wp, bufB, N);

  gemm_bt<<<dim3(mg, 1), 256, 0, stream>>>(bufB, W_lin, b_lin, out, N, OUTF, NF);
}